// Round 9
// baseline (1048.185 us; speedup 1.0000x reference)
//
#include <hip/hip_runtime.h>
#include <hip/hip_bf16.h>

typedef __bf16 bf16x8 __attribute__((ext_vector_type(8)));
typedef __bf16 bf16x4 __attribute__((ext_vector_type(4)));
typedef float f32x4 __attribute__((ext_vector_type(4)));

// ---------------- dtype-robust load helpers ----------------
__device__ __forceinline__ float getf(const void* p, size_t i, int isf32){
  return isf32 ? ((const float*)p)[i]
               : __bfloat162float(((const __hip_bfloat16*)p)[i]);
}
__device__ __forceinline__ int getedge(const void* p, long long idx, int is64, int n){
  long long v = is64 ? ((const long long*)p)[idx] : (long long)((const int*)p)[idx];
  v = v < 0 ? 0 : (v >= n ? (long long)(n - 1) : v);
  return (int)v;
}

__device__ __forceinline__ float bfly_sum(float v){
#pragma unroll
  for (int m = 32; m > 0; m >>= 1) v += __shfl_xor(v, m, 64);
  return v;
}

// ---------------- runtime dtype detection ----------------
__global__ __launch_bounds__(256) void detect_kernel(const void* x, const void* ei,
                                                     int* flags){
  __shared__ int cnt_sane, cnt_odd;
  int t = threadIdx.x;
  if (t == 0){ cnt_sane = 0; cnt_odd = 0; }
  __syncthreads();
  int sane = 0;
  for (int i = t; i < 4096; i += 256){
    float v = __bfloat162float(((const __hip_bfloat16*)x)[i]);
    if (fabsf(v) < 16.f) sane++;
  }
  atomicAdd(&cnt_sane, sane);
  int odd = 0;
  for (int i = t; i < 512; i += 256){
    if (((const int*)ei)[2 * i + 1] != 0) odd++;
  }
  atomicAdd(&cnt_odd, odd);
  __syncthreads();
  if (t == 0){
    flags[0] = (cnt_sane < 3900) ? 1 : 0;  // 1 => float inputs are fp32
    flags[1] = (cnt_odd == 0) ? 1 : 0;     // 1 => edge_index is int64
  }
}

// ---------------- graph bucketing ----------------
__global__ __launch_bounds__(256) void count_kernel(const void* __restrict__ ei, long long E,
                                                    int n, const int* __restrict__ flags,
                                                    int* __restrict__ cnt){
  int i = blockIdx.x * blockDim.x + threadIdx.x;
  if (i < E){
    int d = getedge(ei, E + i, flags[1], n);
    atomicAdd(&cnt[d], 1);
  }
}

__global__ __launch_bounds__(1024) void scan_kernel(const int* __restrict__ cnt, int* __restrict__ off,
                                                    int* __restrict__ pos, int n){
  __shared__ int wsum[16];
  __shared__ int carry_s;
  int tid = threadIdx.x, lane = tid & 63, wv = tid >> 6;
  if (tid == 0) carry_s = 0;
  __syncthreads();
  for (int base = 0; base < n; base += 1024){
    int i = base + tid;
    int v = (i < n) ? cnt[i] : 0;
    int s = v;
#pragma unroll
    for (int o = 1; o < 64; o <<= 1){ int t = __shfl_up(s, o, 64); if (lane >= o) s += t; }
    if (lane == 63) wsum[wv] = s;
    __syncthreads();
    int wo = 0;
    for (int w = 0; w < wv; w++) wo += wsum[w];
    int carry = carry_s;
    int excl = carry + wo + s - v;
    if (i < n){ off[i] = excl; pos[i] = excl; }
    __syncthreads();
    if (tid == 0){
      int tot = 0;
      for (int w = 0; w < 16; w++) tot += wsum[w];
      carry_s = carry + tot;
    }
    __syncthreads();
  }
  if (tid == 0) off[n] = carry_s;
}

__global__ __launch_bounds__(256) void fill_kernel(const void* __restrict__ ei, long long E,
                                                   int n, const int* __restrict__ flags,
                                                   int* __restrict__ pos, int* __restrict__ bsrc){
  int i = blockIdx.x * blockDim.x + threadIdx.x;
  if (i < E){
    int d = getedge(ei, E + i, flags[1], n);
    int s = getedge(ei, i, flags[1], n);
    int p = atomicAdd(&pos[d], 1);
    bsrc[p] = s;
  }
}

// ---------------- bf16 MFMA GEMM: C[M,N] = A[M,K] @ B[K,N] (+bias, relu) ----------------
template<int AMODE, int OMODE, bool RELU, bool BIAS>
__global__ __launch_bounds__(256) void mfma_gemm_kernel(const void* __restrict__ A,
    const void* __restrict__ B, const void* __restrict__ bias, const int* __restrict__ flags,
    void* __restrict__ C, int M, int N, int K)
{
  __shared__ __align__(16) __bf16 sA[128 * 40];
  __shared__ __align__(16) __bf16 sB[64 * 264];
  int f0 = flags[0];
  const bool af32 = (AMODE == 0) || (f0 != 0);
  int t = threadIdx.x;
  int bm = blockIdx.x * 128, bn = blockIdx.y * 64;

  for (int e = t; e < 64 * K; e += 256){
    int nn = e & 63, kk = e >> 6;
    sB[nn * 264 + kk] = (__bf16)getf(B, (size_t)kk * N + bn + nn, f0);
  }

  int wave = t >> 6, lane = t & 63, q = lane >> 4, mi = lane & 15;
  int m0w = (wave & 1) * 64, n0w = (wave >> 1) * 32;
  int k4 = (t & 7) * 4;
  int r0 = t >> 3;
  f32x4 acc[4][2] = {};
  __syncthreads();

  for (int k0 = 0; k0 < K; k0 += 32){
#pragma unroll
    for (int it = 0; it < 4; it++){
      int row = r0 + it * 32;
      int gr = bm + row;
      float vx = 0.f, vy = 0.f, vz = 0.f, vw = 0.f;
      if (gr < M){
        size_t g = (size_t)gr * K + k0 + k4;
        if (af32){
          const f32x4 v = *(const f32x4*)((const float*)A + g);
          vx = v.x; vy = v.y; vz = v.z; vw = v.w;
        } else {
          const __hip_bfloat16* bp8 = (const __hip_bfloat16*)A + g;
          vx = __bfloat162float(bp8[0]); vy = __bfloat162float(bp8[1]);
          vz = __bfloat162float(bp8[2]); vw = __bfloat162float(bp8[3]);
        }
      }
      bf16x4 pk;
      pk.x = (__bf16)vx; pk.y = (__bf16)vy; pk.z = (__bf16)vz; pk.w = (__bf16)vw;
      *(bf16x4*)&sA[row * 40 + k4] = pk;
    }
    __syncthreads();
    bf16x8 bfr0 = *(const bf16x8*)&sB[(n0w + 0 * 16 + mi) * 264 + k0 + q * 8];
    bf16x8 bfr1 = *(const bf16x8*)&sB[(n0w + 1 * 16 + mi) * 264 + k0 + q * 8];
#pragma unroll
    for (int mt = 0; mt < 4; mt++){
      bf16x8 afr = *(const bf16x8*)&sA[(m0w + mt * 16 + mi) * 40 + q * 8];
      acc[mt][0] = __builtin_amdgcn_mfma_f32_16x16x32_bf16(afr, bfr0, acc[mt][0], 0, 0, 0);
      acc[mt][1] = __builtin_amdgcn_mfma_f32_16x16x32_bf16(afr, bfr1, acc[mt][1], 0, 0, 0);
    }
    __syncthreads();
  }

#pragma unroll
  for (int mt = 0; mt < 4; mt++){
    int rowb = bm + m0w + mt * 16 + q * 4;
#pragma unroll
    for (int r = 0; r < 4; r++){
      int row = rowb + r;
      if (row < M){
#pragma unroll
        for (int nt = 0; nt < 2; nt++){
          int col = bn + n0w + nt * 16 + mi;
          float v = acc[mt][nt][r];
          if (BIAS) v += getf(bias, col, f0);
          if (RELU) v = fmaxf(v, 0.f);
          size_t idx = (size_t)row * N + col;
          if (OMODE == 0) ((float*)C)[idx] = v;
          else ((__hip_bfloat16*)C)[idx] = __float2bfloat16(v);
        }
      }
    }
  }
}

// ---------------- attention logits ----------------
__global__ __launch_bounds__(256) void al0_kernel(const __hip_bfloat16* __restrict__ xw,
    const void* __restrict__ a_s, const void* __restrict__ a_d, const int* __restrict__ flags,
    float* __restrict__ als, float* __restrict__ ald, int n)
{
  int f0 = flags[0];
  int i = blockIdx.x, t = threadIdx.x;
  int h = t >> 6, lane = t & 63;
  float v = __bfloat162float(xw[(size_t)i * 256 + t]);
  float ps = v * getf(a_s, t, f0);
  float pd = v * getf(a_d, t, f0);
  ps = bfly_sum(ps); pd = bfly_sum(pd);
  if (lane == 0){ als[(size_t)i * 4 + h] = ps; ald[(size_t)i * 4 + h] = pd; }
}

__global__ __launch_bounds__(128) void al1_kernel(const __hip_bfloat16* __restrict__ xw,
    const void* __restrict__ a_s, const void* __restrict__ a_d, const int* __restrict__ flags,
    float* __restrict__ als, float* __restrict__ ald, int n)
{
  __shared__ float rs[2], rd[2];
  int f0 = flags[0];
  int i = blockIdx.x, t = threadIdx.x;
  int wv = t >> 6, lane = t & 63;
  float v = __bfloat162float(xw[(size_t)i * 128 + t]);
  float ps = v * getf(a_s, t, f0);
  float pd = v * getf(a_d, t, f0);
  ps = bfly_sum(ps); pd = bfly_sum(pd);
  if (lane == 0){ rs[wv] = ps; rd[wv] = pd; }
  __syncthreads();
  if (t == 0){ als[i] = rs[0] + rs[1]; ald[i] = rd[0] + rd[1]; }
}

#define FMA8(U, W) do { \
  macc[0] += (W) * __uint_as_float((U).x << 16); \
  macc[1] += (W) * __uint_as_float((U).x & 0xffff0000u); \
  macc[2] += (W) * __uint_as_float((U).y << 16); \
  macc[3] += (W) * __uint_as_float((U).y & 0xffff0000u); \
  macc[4] += (W) * __uint_as_float((U).z << 16); \
  macc[5] += (W) * __uint_as_float((U).z & 0xffff0000u); \
  macc[6] += (W) * __uint_as_float((U).w << 16); \
  macc[7] += (W) * __uint_as_float((U).w & 0xffff0000u); \
} while (0)

// ---------------- agg0: wave-per-node; per-lane broadcast-load weights (no bpermute) ----------------
__global__ __launch_bounds__(256) void agg0_kernel(
    const __hip_bfloat16* __restrict__ xw, const float* __restrict__ als, const float* __restrict__ ald,
    const int* __restrict__ bsrc, const int* __restrict__ off,
    const void* __restrict__ bias, const void* __restrict__ gamma,
    const void* __restrict__ beta, const int* __restrict__ flags,
    float* __restrict__ res_out, int n)
{
  int f0 = flags[0];
  int wv = threadIdx.x >> 6, lane = threadIdx.x & 63;
  int i = blockIdx.x * 4 + wv;
  if (i >= n) return;
  int e0 = off[i];
  int deg = off[i + 1] - e0;
  int tot = deg + 1;                    // + self loop

  int h4 = lane & 3;
  int e16 = lane >> 2;
  float ad_h = ald[(size_t)i * 4 + h4];

  // ---- softmax stats (segmented bfly over 16 lanes per head) ----
  float m = -1e30f;
  for (int b = 0; b < tot; b += 16){
    int j = b + e16;
    if (j < tot){
      int s = (j < deg) ? bsrc[e0 + j] : i;
      float e = als[(size_t)s * 4 + h4] + ad_h;
      e = (e > 0.f) ? e : 0.2f * e;
      m = fmaxf(m, e);
    }
  }
#pragma unroll
  for (int mk = 4; mk < 64; mk <<= 1) m = fmaxf(m, __shfl_xor(m, mk, 64));
  float l = 0.f;
  for (int b = 0; b < tot; b += 16){
    int j = b + e16;
    if (j < tot){
      int s = (j < deg) ? bsrc[e0 + j] : i;
      float e = als[(size_t)s * 4 + h4] + ad_h;
      e = (e > 0.f) ? e : 0.2f * e;
      l += __expf(e - m);
    }
  }
#pragma unroll
  for (int mk = 4; mk < 64; mk <<= 1) l += __shfl_xor(l, mk, 64);
  float linv = 1.f / l;

  // ---- per-lane head constants (one static shuffle each, outside loops) ----
  int ch0 = (lane & 31) * 8;
  int headc = (lane & 31) >> 3;         // this lane's head = ch0/64
  int esub = lane >> 5;                 // 0,1
  float m_c    = __shfl(m, headc, 64);      // stats live in lanes 0..3
  float linv_c = __shfl(linv, headc, 64);
  float ad_c   = __shfl(ad_h, headc, 64);
  const __hip_bfloat16* xp = xw + ch0;
  float macc[8] = {};

  // ---- gather: each lane recomputes (row, weight) via broadcast loads; 8 rows in flight ----
  for (int b = 0; b < tot; b += 16){
    int sreg[8];
#pragma unroll
    for (int u = 0; u < 8; u++){
      int j = b + (u << 1) + esub;
      int jc = min(j, tot - 1);
      sreg[u] = (jc < deg) ? bsrc[e0 + jc] : i;   // broadcast load (same addr across 32 lanes)
    }
    uint4 U[8]; float A[8];
#pragma unroll
    for (int u = 0; u < 8; u++){
      U[u] = *(const uint4*)(xp + (size_t)sreg[u] * 256);
      A[u] = als[(size_t)sreg[u] * 4 + headc];    // broadcast load
    }
#pragma unroll
    for (int u = 0; u < 8; u++){
      int j = b + (u << 1) + esub;
      float e = A[u] + ad_c;
      e = (e > 0.f) ? e : 0.2f * e;
      float W = (j < tot) ? __expf(e - m_c) * linv_c : 0.f;
      FMA8(U[u], W);
    }
  }

  // fold the two edge-halves (lane ^ 32 holds same channels)
#pragma unroll
  for (int k = 0; k < 8; k++) macc[k] += __shfl_xor(macc[k], 32, 64);

  // ---- bias + LN + residual + relu ----
  float v[8]; float s1 = 0.f;
#pragma unroll
  for (int k = 0; k < 8; k++){ v[k] = macc[k] + getf(bias, ch0 + k, f0); s1 += v[k]; }
#pragma unroll
  for (int mk = 1; mk < 32; mk <<= 1) s1 += __shfl_xor(s1, mk, 64);
  float mu = s1 * (1.f / 256.f);
  float s2 = 0.f;
#pragma unroll
  for (int k = 0; k < 8; k++){ v[k] -= mu; s2 += v[k] * v[k]; }
#pragma unroll
  for (int mk = 1; mk < 32; mk <<= 1) s2 += __shfl_xor(s2, mk, 64);
  float rstd = rsqrtf(s2 * (1.f / 256.f) + 1e-5f);
  float y[8];
  const float* rr = res_out + (size_t)i * 256 + ch0;
#pragma unroll
  for (int k = 0; k < 8; k++){
    float t = v[k] * rstd * getf(gamma, ch0 + k, f0) + getf(beta, ch0 + k, f0);
    t += rr[k];
    y[k] = fmaxf(t, 0.f);
  }
  f32x4 st;
  int o4 = esub * 4;
  st.x = y[o4]; st.y = y[o4 + 1]; st.z = y[o4 + 2]; st.w = y[o4 + 3];
  *(f32x4*)(res_out + (size_t)i * 256 + ch0 + o4) = st;
}

// ---------------- agg1: wave-per-node, H=1, C=128; broadcast-load weights ----------------
__global__ __launch_bounds__(256) void agg1_kernel(
    const __hip_bfloat16* __restrict__ xw, const float* __restrict__ als, const float* __restrict__ ald,
    const int* __restrict__ bsrc, const int* __restrict__ off,
    const void* __restrict__ bias, const void* __restrict__ gamma,
    const void* __restrict__ beta, const int* __restrict__ flags,
    float* __restrict__ outp, int n)
{
  int f0 = flags[0];
  int wv = threadIdx.x >> 6, lane = threadIdx.x & 63;
  int i = blockIdx.x * 4 + wv;
  if (i >= n) return;
  int e0 = off[i];
  int deg = off[i + 1] - e0;
  int tot = deg + 1;

  float ad_i = ald[i];
  float m = -1e30f;
  for (int b = 0; b < tot; b += 64){
    int j = b + lane;
    if (j < tot){
      int s = (j < deg) ? bsrc[e0 + j] : i;
      float e = als[s] + ad_i;
      e = (e > 0.f) ? e : 0.2f * e;
      m = fmaxf(m, e);
    }
  }
#pragma unroll
  for (int mk = 1; mk < 64; mk <<= 1) m = fmaxf(m, __shfl_xor(m, mk, 64));
  float l = 0.f;
  for (int b = 0; b < tot; b += 64){
    int j = b + lane;
    if (j < tot){
      int s = (j < deg) ? bsrc[e0 + j] : i;
      float e = als[s] + ad_i;
      e = (e > 0.f) ? e : 0.2f * e;
      l += __expf(e - m);
    }
  }
#pragma unroll
  for (int mk = 1; mk < 64; mk <<= 1) l += __shfl_xor(l, mk, 64);
  float linv = 1.f / l;

  int ch0 = (lane & 15) * 8;
  int esub = lane >> 4;                  // 0..3
  const __hip_bfloat16* xp = xw + ch0;
  float macc[8] = {};

  for (int b = 0; b < tot; b += 32){
    int sreg[8];
#pragma unroll
    for (int u = 0; u < 8; u++){
      int j = b + (u << 2) + esub;
      int jc = min(j, tot - 1);
      sreg[u] = (jc < deg) ? bsrc[e0 + jc] : i;
    }
    uint4 U[8]; float A[8];
#pragma unroll
    for (int u = 0; u < 8; u++){
      U[u] = *(const uint4*)(xp + (size_t)sreg[u] * 128);
      A[u] = als[sreg[u]];
    }
#pragma unroll
    for (int u = 0; u < 8; u++){
      int j = b + (u << 2) + esub;
      float e = A[u] + ad_i;
      e = (e > 0.f) ? e : 0.2f * e;
      float W = (j < tot) ? __expf(e - m) * linv : 0.f;
      FMA8(U[u], W);
    }
  }

#pragma unroll
  for (int k = 0; k < 8; k++){
    macc[k] += __shfl_xor(macc[k], 16, 64);
    macc[k] += __shfl_xor(macc[k], 32, 64);
  }

  float v[8]; float s1 = 0.f;
#pragma unroll
  for (int k = 0; k < 8; k++){ v[k] = macc[k] + getf(bias, ch0 + k, f0); s1 += v[k]; }
#pragma unroll
  for (int mk = 1; mk < 16; mk <<= 1) s1 += __shfl_xor(s1, mk, 64);
  float mu = s1 * (1.f / 128.f);
  float s2 = 0.f;
#pragma unroll
  for (int k = 0; k < 8; k++){ v[k] -= mu; s2 += v[k] * v[k]; }
#pragma unroll
  for (int mk = 1; mk < 16; mk <<= 1) s2 += __shfl_xor(s2, mk, 64);
  float rstd = rsqrtf(s2 * (1.f / 128.f) + 1e-5f);
  float y[8];
#pragma unroll
  for (int k = 0; k < 8; k++)
    y[k] = v[k] * rstd * getf(gamma, ch0 + k, f0) + getf(beta, ch0 + k, f0);
  int o2 = esub * 2;
  float2 st; st.x = y[o2]; st.y = y[o2 + 1];
  *(float2*)(outp + (size_t)i * 128 + ch0 + o2) = st;
}

// ---------------- row L2-normalize ----------------
__global__ __launch_bounds__(128) void norm_kernel(const float* __restrict__ in,
                                                   float* __restrict__ outp, int n)
{
  __shared__ float sred[2];
  int i = blockIdx.x, t = threadIdx.x, wv = t >> 6, lane = t & 63;
  float v = in[(size_t)i * 128 + t];
  float ss = bfly_sum(v * v);
  if (lane == 0) sred[wv] = ss;
  __syncthreads();
  float inv = 1.f / fmaxf(sqrtf(sred[0] + sred[1]), 1e-12f);
  outp[(size_t)i * 128 + t] = v * inv;
}

// ---------------- launch ----------------
extern "C" void kernel_launch(void* const* d_in, const int* in_sizes, int n_in,
                              void* d_out, int out_size, void* d_ws, size_t ws_size,
                              hipStream_t stream)
{
  const void* x   = d_in[0];
  const void* ei  = d_in[1];
  const void* Wp  = d_in[2];
  const void* bp  = d_in[3];
  const void* W0  = d_in[4];
  const void* as0 = d_in[5];
  const void* ad0 = d_in[6];
  const void* b0  = d_in[7];
  const void* W1  = d_in[8];
  const void* as1 = d_in[9];
  const void* ad1 = d_in[10];
  const void* b1  = d_in[11];
  const void* g0  = d_in[12];
  const void* be0 = d_in[13];
  const void* g1  = d_in[14];
  const void* be1 = d_in[15];
  const void* Wo  = d_in[16];
  const void* bo  = d_in[17];
  float* outp = (float*)d_out;

  const int n = in_sizes[0] / 256;   // 50000
  const int E = in_sizes[1] / 2;     // 800000

  char* w = (char*)d_ws;
  size_t SZ = (size_t)n * 256 * sizeof(float);
  float* h_buf  = (float*)w;                         // h -> h1 -> h2 (fp32)
  char*  xw_reg = w + SZ;
  __hip_bfloat16* xw_bf = (__hip_bfloat16*)xw_reg;
  float* prenorm = (float*)xw_reg;
  char* p = w + 2 * SZ;
  int* flags = (int*)p; p += 64;
  float* als0 = (float*)p; p += (size_t)n * 4 * sizeof(float);
  float* ald0 = (float*)p; p += (size_t)n * 4 * sizeof(float);
  float* als1 = (float*)p; p += (size_t)n * sizeof(float);
  float* ald1 = (float*)p; p += (size_t)n * sizeof(float);
  int* cnt  = (int*)p; p += (size_t)n * sizeof(int);
  int* offb = (int*)p; p += (size_t)(n + 1) * sizeof(int) + 4;
  int* pos  = (int*)p; p += (size_t)n * sizeof(int);
  int* bsrc = (int*)p; p += (size_t)E * sizeof(int);

  detect_kernel<<<1, 256, 0, stream>>>(x, ei, flags);

  hipMemsetAsync(cnt, 0, (size_t)n * sizeof(int), stream);
  count_kernel<<<(E + 255) / 256, 256, 0, stream>>>(ei, E, n, flags, cnt);
  scan_kernel<<<1, 1024, 0, stream>>>(cnt, offb, pos, n);
  fill_kernel<<<(E + 255) / 256, 256, 0, stream>>>(ei, E, n, flags, pos, bsrc);

  int gm = (n + 127) / 128;
  // h = relu(x @ Wp + bp)  (fp32 out)
  mfma_gemm_kernel<1, 0, true, true><<<dim3(gm, 4), 256, 0, stream>>>(x, Wp, bp, flags, h_buf, n, 256, 256);
  // xw0 = h @ W0  (bf16 out)
  mfma_gemm_kernel<0, 1, false, false><<<dim3(gm, 4), 256, 0, stream>>>(h_buf, W0, nullptr, flags, xw_bf, n, 256, 256);
  al0_kernel<<<n, 256, 0, stream>>>(xw_bf, as0, ad0, flags, als0, ald0, n);
  // layer-0 aggregate + b0 + LN + residual + relu (in-place on h_buf)
  agg0_kernel<<<(n + 3) / 4, 256, 0, stream>>>(xw_bf, als0, ald0, bsrc, offb, b0, g0, be0, flags, h_buf, n);
  // xw1 = h1 @ W1  (bf16 out)
  mfma_gemm_kernel<0, 1, false, false><<<dim3(gm, 2), 256, 0, stream>>>(h_buf, W1, nullptr, flags, xw_bf, n, 128, 256);
  al1_kernel<<<n, 128, 0, stream>>>(xw_bf, as1, ad1, flags, als1, ald1, n);
  // layer-1 aggregate + b1 + LN -> h2 (h_buf as n x 128)
  agg1_kernel<<<(n + 3) / 4, 256, 0, stream>>>(xw_bf, als1, ald1, bsrc, offb, b1, g1, be1, flags, h_buf, n);
  // pre-norm = h2 @ Wo + bo
  mfma_gemm_kernel<0, 0, false, true><<<dim3(gm, 2), 256, 0, stream>>>(h_buf, Wo, bo, flags, prenorm, n, 128, 128);
  // out = row-normalize
  norm_kernel<<<n, 128, 0, stream>>>(prenorm, outp, n);
}

// Round 10
// 873.668 us; speedup vs baseline: 1.1998x; 1.1998x over previous
//
#include <hip/hip_runtime.h>
#include <hip/hip_bf16.h>

typedef __bf16 bf16x8 __attribute__((ext_vector_type(8)));
typedef __bf16 bf16x4 __attribute__((ext_vector_type(4)));
typedef float f32x4 __attribute__((ext_vector_type(4)));

// ---------------- dtype-robust load helpers ----------------
__device__ __forceinline__ float getf(const void* p, size_t i, int isf32){
  return isf32 ? ((const float*)p)[i]
               : __bfloat162float(((const __hip_bfloat16*)p)[i]);
}
__device__ __forceinline__ int getedge(const void* p, long long idx, int is64, int n){
  long long v = is64 ? ((const long long*)p)[idx] : (long long)((const int*)p)[idx];
  v = v < 0 ? 0 : (v >= n ? (long long)(n - 1) : v);
  return (int)v;
}

__device__ __forceinline__ float bfly_sum(float v){
#pragma unroll
  for (int m = 32; m > 0; m >>= 1) v += __shfl_xor(v, m, 64);
  return v;
}

// ---------------- runtime dtype detection ----------------
__global__ __launch_bounds__(256) void detect_kernel(const void* x, const void* ei,
                                                     int* flags){
  __shared__ int cnt_sane, cnt_odd;
  int t = threadIdx.x;
  if (t == 0){ cnt_sane = 0; cnt_odd = 0; }
  __syncthreads();
  int sane = 0;
  for (int i = t; i < 4096; i += 256){
    float v = __bfloat162float(((const __hip_bfloat16*)x)[i]);
    if (fabsf(v) < 16.f) sane++;
  }
  atomicAdd(&cnt_sane, sane);
  int odd = 0;
  for (int i = t; i < 512; i += 256){
    if (((const int*)ei)[2 * i + 1] != 0) odd++;
  }
  atomicAdd(&cnt_odd, odd);
  __syncthreads();
  if (t == 0){
    flags[0] = (cnt_sane < 3900) ? 1 : 0;  // 1 => float inputs are fp32
    flags[1] = (cnt_odd == 0) ? 1 : 0;     // 1 => edge_index is int64
  }
}

// ---------------- graph bucketing ----------------
__global__ __launch_bounds__(256) void count_kernel(const void* __restrict__ ei, long long E,
                                                    int n, const int* __restrict__ flags,
                                                    int* __restrict__ cnt){
  int i = blockIdx.x * blockDim.x + threadIdx.x;
  if (i < E){
    int d = getedge(ei, E + i, flags[1], n);
    atomicAdd(&cnt[d], 1);
  }
}

__global__ __launch_bounds__(1024) void scan_kernel(const int* __restrict__ cnt, int* __restrict__ off,
                                                    int* __restrict__ pos, int n){
  __shared__ int wsum[16];
  __shared__ int carry_s;
  int tid = threadIdx.x, lane = tid & 63, wv = tid >> 6;
  if (tid == 0) carry_s = 0;
  __syncthreads();
  for (int base = 0; base < n; base += 1024){
    int i = base + tid;
    int v = (i < n) ? cnt[i] : 0;
    int s = v;
#pragma unroll
    for (int o = 1; o < 64; o <<= 1){ int t = __shfl_up(s, o, 64); if (lane >= o) s += t; }
    if (lane == 63) wsum[wv] = s;
    __syncthreads();
    int wo = 0;
    for (int w = 0; w < wv; w++) wo += wsum[w];
    int carry = carry_s;
    int excl = carry + wo + s - v;
    if (i < n){ off[i] = excl; pos[i] = excl; }
    __syncthreads();
    if (tid == 0){
      int tot = 0;
      for (int w = 0; w < 16; w++) tot += wsum[w];
      carry_s = carry + tot;
    }
    __syncthreads();
  }
  if (tid == 0) off[n] = carry_s;
}

__global__ __launch_bounds__(256) void fill_kernel(const void* __restrict__ ei, long long E,
                                                   int n, const int* __restrict__ flags,
                                                   int* __restrict__ pos, int* __restrict__ bsrc,
                                                   int* __restrict__ bdst){
  int i = blockIdx.x * blockDim.x + threadIdx.x;
  if (i < E){
    int d = getedge(ei, E + i, flags[1], n);
    int s = getedge(ei, i, flags[1], n);
    int p = atomicAdd(&pos[d], 1);
    bsrc[p] = s;
    bdst[p] = d;
  }
}

// ---------------- bf16 MFMA GEMM: C[M,N] = A[M,K] @ B[K,N] (+bias, relu) ----------------
template<int AMODE, int OMODE, bool RELU, bool BIAS>
__global__ __launch_bounds__(256) void mfma_gemm_kernel(const void* __restrict__ A,
    const void* __restrict__ B, const void* __restrict__ bias, const int* __restrict__ flags,
    void* __restrict__ C, int M, int N, int K)
{
  __shared__ __align__(16) __bf16 sA[128 * 40];
  __shared__ __align__(16) __bf16 sB[64 * 264];
  int f0 = flags[0];
  const bool af32 = (AMODE == 0) || (f0 != 0);
  int t = threadIdx.x;
  int bm = blockIdx.x * 128, bn = blockIdx.y * 64;

  for (int e = t; e < 64 * K; e += 256){
    int nn = e & 63, kk = e >> 6;
    sB[nn * 264 + kk] = (__bf16)getf(B, (size_t)kk * N + bn + nn, f0);
  }

  int wave = t >> 6, lane = t & 63, q = lane >> 4, mi = lane & 15;
  int m0w = (wave & 1) * 64, n0w = (wave >> 1) * 32;
  int k4 = (t & 7) * 4;
  int r0 = t >> 3;
  f32x4 acc[4][2] = {};
  __syncthreads();

  for (int k0 = 0; k0 < K; k0 += 32){
#pragma unroll
    for (int it = 0; it < 4; it++){
      int row = r0 + it * 32;
      int gr = bm + row;
      float vx = 0.f, vy = 0.f, vz = 0.f, vw = 0.f;
      if (gr < M){
        size_t g = (size_t)gr * K + k0 + k4;
        if (af32){
          const f32x4 v = *(const f32x4*)((const float*)A + g);
          vx = v.x; vy = v.y; vz = v.z; vw = v.w;
        } else {
          const __hip_bfloat16* bp8 = (const __hip_bfloat16*)A + g;
          vx = __bfloat162float(bp8[0]); vy = __bfloat162float(bp8[1]);
          vz = __bfloat162float(bp8[2]); vw = __bfloat162float(bp8[3]);
        }
      }
      bf16x4 pk;
      pk.x = (__bf16)vx; pk.y = (__bf16)vy; pk.z = (__bf16)vz; pk.w = (__bf16)vw;
      *(bf16x4*)&sA[row * 40 + k4] = pk;
    }
    __syncthreads();
    bf16x8 bfr0 = *(const bf16x8*)&sB[(n0w + 0 * 16 + mi) * 264 + k0 + q * 8];
    bf16x8 bfr1 = *(const bf16x8*)&sB[(n0w + 1 * 16 + mi) * 264 + k0 + q * 8];
#pragma unroll
    for (int mt = 0; mt < 4; mt++){
      bf16x8 afr = *(const bf16x8*)&sA[(m0w + mt * 16 + mi) * 40 + q * 8];
      acc[mt][0] = __builtin_amdgcn_mfma_f32_16x16x32_bf16(afr, bfr0, acc[mt][0], 0, 0, 0);
      acc[mt][1] = __builtin_amdgcn_mfma_f32_16x16x32_bf16(afr, bfr1, acc[mt][1], 0, 0, 0);
    }
    __syncthreads();
  }

#pragma unroll
  for (int mt = 0; mt < 4; mt++){
    int rowb = bm + m0w + mt * 16 + q * 4;
#pragma unroll
    for (int r = 0; r < 4; r++){
      int row = rowb + r;
      if (row < M){
#pragma unroll
        for (int nt = 0; nt < 2; nt++){
          int col = bn + n0w + nt * 16 + mi;
          float v = acc[mt][nt][r];
          if (BIAS) v += getf(bias, col, f0);
          if (RELU) v = fmaxf(v, 0.f);
          size_t idx = (size_t)row * N + col;
          if (OMODE == 0) ((float*)C)[idx] = v;
          else ((__hip_bfloat16*)C)[idx] = __float2bfloat16(v);
        }
      }
    }
  }
}

// ---------------- attention logits ----------------
__global__ __launch_bounds__(256) void al0_kernel(const __hip_bfloat16* __restrict__ xw,
    const void* __restrict__ a_s, const void* __restrict__ a_d, const int* __restrict__ flags,
    float* __restrict__ als, float* __restrict__ ald, int n)
{
  int f0 = flags[0];
  int i = blockIdx.x, t = threadIdx.x;
  int h = t >> 6, lane = t & 63;
  float v = __bfloat162float(xw[(size_t)i * 256 + t]);
  float ps = v * getf(a_s, t, f0);
  float pd = v * getf(a_d, t, f0);
  ps = bfly_sum(ps); pd = bfly_sum(pd);
  if (lane == 0){ als[(size_t)i * 4 + h] = ps; ald[(size_t)i * 4 + h] = pd; }
}

__global__ __launch_bounds__(128) void al1_kernel(const __hip_bfloat16* __restrict__ xw,
    const void* __restrict__ a_s, const void* __restrict__ a_d, const int* __restrict__ flags,
    float* __restrict__ als, float* __restrict__ ald, int n)
{
  __shared__ float rs[2], rd[2];
  int f0 = flags[0];
  int i = blockIdx.x, t = threadIdx.x;
  int wv = t >> 6, lane = t & 63;
  float v = __bfloat162float(xw[(size_t)i * 128 + t]);
  float ps = v * getf(a_s, t, f0);
  float pd = v * getf(a_d, t, f0);
  ps = bfly_sum(ps); pd = bfly_sum(pd);
  if (lane == 0){ rs[wv] = ps; rd[wv] = pd; }
  __syncthreads();
  if (t == 0){ als[i] = rs[0] + rs[1]; ald[i] = rd[0] + rd[1]; }
}

// ---------------- edge weight kernels: w = exp(leaky(als[src]+ald[dst])) ----------------
__global__ __launch_bounds__(256) void wq0_kernel(const float* __restrict__ als,
    const float* __restrict__ ald, const int* __restrict__ bsrc, const int* __restrict__ bdst,
    f32x4* __restrict__ wq, int E)
{
  int p = blockIdx.x * 256 + threadIdx.x;
  if (p < E){
    int s = bsrc[p], d = bdst[p];
    f32x4 a = ((const f32x4*)als)[s];
    f32x4 b = ((const f32x4*)ald)[d];
    f32x4 w;
#pragma unroll
    for (int k = 0; k < 4; k++){
      float e = a[k] + b[k];
      e = (e > 0.f) ? e : 0.2f * e;
      w[k] = __expf(e);
    }
    wq[p] = w;
  }
}

__global__ __launch_bounds__(256) void wq1_kernel(const float* __restrict__ als,
    const float* __restrict__ ald, const int* __restrict__ bsrc, const int* __restrict__ bdst,
    float* __restrict__ wq, int E)
{
  int p = blockIdx.x * 256 + threadIdx.x;
  if (p < E){
    float e = als[bsrc[p]] + ald[bdst[p]];
    e = (e > 0.f) ? e : 0.2f * e;
    wq[p] = __expf(e);
  }
}

#define FMA8(U, W) do { \
  macc[0] += (W) * __uint_as_float((U).x << 16); \
  macc[1] += (W) * __uint_as_float((U).x & 0xffff0000u); \
  macc[2] += (W) * __uint_as_float((U).y << 16); \
  macc[3] += (W) * __uint_as_float((U).y & 0xffff0000u); \
  macc[4] += (W) * __uint_as_float((U).z << 16); \
  macc[5] += (W) * __uint_as_float((U).z & 0xffff0000u); \
  macc[6] += (W) * __uint_as_float((U).w << 16); \
  macc[7] += (W) * __uint_as_float((U).w & 0xffff0000u); \
} while (0)

// ---------------- gather0: block-per-node, precomputed weights, on-the-fly denominator ----------------
__global__ __launch_bounds__(256) void gather0_kernel(
    const __hip_bfloat16* __restrict__ xw, const float* __restrict__ als, const float* __restrict__ ald,
    const int* __restrict__ bsrc, const float* __restrict__ wq, const int* __restrict__ off,
    const void* __restrict__ bias, const void* __restrict__ gamma,
    const void* __restrict__ beta, const int* __restrict__ flags,
    float* __restrict__ res_out, int n)
{
  int f0 = flags[0];
  int i = blockIdx.x;
  int t = threadIdx.x, wv = t >> 6, lane = t & 63;
  int e0 = off[i];
  int jend = off[i + 1];
  int ch0 = (lane & 31) * 8;
  int headc = (lane & 31) >> 3;
  int esub = lane >> 5;               // 0,1
  const __hip_bfloat16* xp = xw + ch0;

  __shared__ float sp[4][264];
  __shared__ float slh[4][4];
  __shared__ float s_red[4];

  float macc[8] = {};
  float wacc = 0.f;

  // self-loop (added once: wave 0, esub 0)
  float selfe = als[(size_t)i * 4 + headc] + ald[(size_t)i * 4 + headc];
  selfe = (selfe > 0.f) ? selfe : 0.2f * selfe;
  float eself = __expf(selfe);
  if (wv == 0 && esub == 0){
    uint4 u = *(const uint4*)(xp + (size_t)i * 256);
    FMA8(u, eself);
  }

  // edges: slot = wv*2+esub (0..7), stride 8, 4-deep pipeline
  int slot = wv * 2 + esub;
  for (int j = e0 + slot; j < jend; j += 32){
    int jA = j, jB = j + 8, jC = j + 16, jD = j + 24;
    int cA = jA, cB = min(jB, jend - 1), cC = min(jC, jend - 1), cD = min(jD, jend - 1);
    int sA = bsrc[cA], sB_ = bsrc[cB], sC = bsrc[cC], sD = bsrc[cD];
    float WA = wq[(size_t)cA * 4 + headc];
    float WB = wq[(size_t)cB * 4 + headc];
    float WC = wq[(size_t)cC * 4 + headc];
    float WD = wq[(size_t)cD * 4 + headc];
    uint4 UA = *(const uint4*)(xp + (size_t)sA * 256);
    uint4 UB = *(const uint4*)(xp + (size_t)sB_ * 256);
    uint4 UC = *(const uint4*)(xp + (size_t)sC * 256);
    uint4 UD = *(const uint4*)(xp + (size_t)sD * 256);
    WB = (jB < jend) ? WB : 0.f;
    WC = (jC < jend) ? WC : 0.f;
    WD = (jD < jend) ? WD : 0.f;
    wacc += WA + WB + WC + WD;
    FMA8(UA, WA); FMA8(UB, WB); FMA8(UC, WC); FMA8(UD, WD);
  }

  // fold esub halves (lane ^ 32 holds same channels / same head)
#pragma unroll
  for (int k = 0; k < 8; k++) macc[k] += __shfl_xor(macc[k], 32, 64);
  wacc += __shfl_xor(wacc, 32, 64);

  if (lane < 32){
    *(f32x4*)&sp[wv][ch0]     = (f32x4){macc[0], macc[1], macc[2], macc[3]};
    *(f32x4*)&sp[wv][ch0 + 4] = (f32x4){macc[4], macc[5], macc[6], macc[7]};
    if ((lane & 7) == 0) slh[wv][headc] = wacc;
  }
  __syncthreads();

  // thread t = channel t
  int hh = t >> 6;
  float selft = als[(size_t)i * 4 + hh] + ald[(size_t)i * 4 + hh];
  selft = (selft > 0.f) ? selft : 0.2f * selft;
  float lsum = slh[0][hh] + slh[1][hh] + slh[2][hh] + slh[3][hh] + __expf(selft);
  float v = (sp[0][t] + sp[1][t] + sp[2][t] + sp[3][t]) / lsum + getf(bias, t, f0);

  // LayerNorm over 256 channels
  float s1 = bfly_sum(v);
  if (lane == 0) s_red[wv] = s1;
  __syncthreads();
  float mu = (s_red[0] + s_red[1] + s_red[2] + s_red[3]) * (1.f / 256.f);
  __syncthreads();
  float d = v - mu;
  float s2 = bfly_sum(d * d);
  if (lane == 0) s_red[wv] = s2;
  __syncthreads();
  float var = (s_red[0] + s_red[1] + s_red[2] + s_red[3]) * (1.f / 256.f);
  float y = d * rsqrtf(var + 1e-5f) * getf(gamma, t, f0) + getf(beta, t, f0);
  y = y + res_out[(size_t)i * 256 + t];
  y = fmaxf(y, 0.f);
  res_out[(size_t)i * 256 + t] = y;
}

// ---------------- gather1: block-per-node, H=1, C=128 ----------------
__global__ __launch_bounds__(256) void gather1_kernel(
    const __hip_bfloat16* __restrict__ xw, const float* __restrict__ als, const float* __restrict__ ald,
    const int* __restrict__ bsrc, const float* __restrict__ wq, const int* __restrict__ off,
    const void* __restrict__ bias, const void* __restrict__ gamma,
    const void* __restrict__ beta, const int* __restrict__ flags,
    float* __restrict__ outp, int n)
{
  int f0 = flags[0];
  int i = blockIdx.x;
  int t = threadIdx.x, wv = t >> 6, lane = t & 63;
  int e0 = off[i];
  int jend = off[i + 1];
  int ch0 = (lane & 15) * 8;
  int esub = lane >> 4;               // 0..3
  const __hip_bfloat16* xp = xw + ch0;

  __shared__ float sp[4][136];
  __shared__ float slh[4];
  __shared__ float s_red[2];

  float macc[8] = {};
  float wacc = 0.f;

  float selfe = als[i] + ald[i];
  selfe = (selfe > 0.f) ? selfe : 0.2f * selfe;
  float eself = __expf(selfe);
  if (wv == 0 && esub == 0){
    uint4 u = *(const uint4*)(xp + (size_t)i * 128);
    FMA8(u, eself);
  }

  // slot = wv*4+esub (0..15), stride 16, 2-deep pipeline
  int slot = wv * 4 + esub;
  for (int j = e0 + slot; j < jend; j += 32){
    int jA = j, jB = j + 16;
    int cB = min(jB, jend - 1);
    int sA = bsrc[jA], sB_ = bsrc[cB];
    float WA = wq[jA];
    float WB = wq[cB];
    uint4 UA = *(const uint4*)(xp + (size_t)sA * 128);
    uint4 UB = *(const uint4*)(xp + (size_t)sB_ * 128);
    WB = (jB < jend) ? WB : 0.f;
    wacc += WA + WB;
    FMA8(UA, WA); FMA8(UB, WB);
  }

  // fold esub groups: xor16 then xor32
#pragma unroll
  for (int k = 0; k < 8; k++){
    macc[k] += __shfl_xor(macc[k], 16, 64);
    macc[k] += __shfl_xor(macc[k], 32, 64);
  }
  wacc += __shfl_xor(wacc, 16, 64);
  wacc += __shfl_xor(wacc, 32, 64);

  if (lane < 16){
    *(f32x4*)&sp[wv][ch0]     = (f32x4){macc[0], macc[1], macc[2], macc[3]};
    *(f32x4*)&sp[wv][ch0 + 4] = (f32x4){macc[4], macc[5], macc[6], macc[7]};
    if (lane == 0) slh[wv] = wacc;
  }
  __syncthreads();

  float y = 0.f;
  if (t < 128){
    float lsum = slh[0] + slh[1] + slh[2] + slh[3] + eself;
    float v = (sp[0][t] + sp[1][t] + sp[2][t] + sp[3][t]) / lsum + getf(bias, t, f0);
    float s1 = bfly_sum(v);
    if (lane == 0) s_red[wv] = s1;
    __syncthreads();
    float mu = (s_red[0] + s_red[1]) * (1.f / 128.f);
    __syncthreads();
    float d = v - mu;
    float s2 = bfly_sum(d * d);
    if (lane == 0) s_red[wv] = s2;
    __syncthreads();
    float var = (s_red[0] + s_red[1]) * (1.f / 128.f);
    y = d * rsqrtf(var + 1e-5f) * getf(gamma, t, f0) + getf(beta, t, f0);
    outp[(size_t)i * 128 + t] = y;
  } else {
    __syncthreads(); __syncthreads(); __syncthreads();
  }
}

// ---------------- row L2-normalize ----------------
__global__ __launch_bounds__(128) void norm_kernel(const float* __restrict__ in,
                                                   float* __restrict__ outp, int n)
{
  __shared__ float sred[2];
  int i = blockIdx.x, t = threadIdx.x, wv = t >> 6, lane = t & 63;
  float v = in[(size_t)i * 128 + t];
  float ss = bfly_sum(v * v);
  if (lane == 0) sred[wv] = ss;
  __syncthreads();
  float inv = 1.f / fmaxf(sqrtf(sred[0] + sred[1]), 1e-12f);
  outp[(size_t)i * 128 + t] = v * inv;
}

// ---------------- launch ----------------
extern "C" void kernel_launch(void* const* d_in, const int* in_sizes, int n_in,
                              void* d_out, int out_size, void* d_ws, size_t ws_size,
                              hipStream_t stream)
{
  const void* x   = d_in[0];
  const void* ei  = d_in[1];
  const void* Wp  = d_in[2];
  const void* bp  = d_in[3];
  const void* W0  = d_in[4];
  const void* as0 = d_in[5];
  const void* ad0 = d_in[6];
  const void* b0  = d_in[7];
  const void* W1  = d_in[8];
  const void* as1 = d_in[9];
  const void* ad1 = d_in[10];
  const void* b1  = d_in[11];
  const void* g0  = d_in[12];
  const void* be0 = d_in[13];
  const void* g1  = d_in[14];
  const void* be1 = d_in[15];
  const void* Wo  = d_in[16];
  const void* bo  = d_in[17];
  float* outp = (float*)d_out;

  const int n = in_sizes[0] / 256;   // 50000
  const int E = in_sizes[1] / 2;     // 800000

  char* w = (char*)d_ws;
  size_t SZ = (size_t)n * 256 * sizeof(float);
  float* h_buf  = (float*)w;                         // h -> h1 -> h2 (fp32)
  char*  xw_reg = w + SZ;
  __hip_bfloat16* xw_bf = (__hip_bfloat16*)xw_reg;
  float* prenorm = (float*)xw_reg;
  char* p = w + 2 * SZ;
  int* flags = (int*)p; p += 64;
  float* als0 = (float*)p; p += (size_t)n * 4 * sizeof(float);
  float* ald0 = (float*)p; p += (size_t)n * 4 * sizeof(float);
  float* als1 = (float*)p; p += (size_t)n * sizeof(float);
  float* ald1 = (float*)p; p += (size_t)n * sizeof(float);
  int* cnt  = (int*)p; p += (size_t)n * sizeof(int);
  int* offb = (int*)p; p += (size_t)(n + 1) * sizeof(int) + 4;
  int* pos  = (int*)p; p += (size_t)n * sizeof(int);
  int* bsrc = (int*)p; p += (size_t)E * sizeof(int);
  int* bdst = (int*)p; p += (size_t)E * sizeof(int);
  float* wqbuf = (float*)p; p += ((size_t)E + 64) * 4 * sizeof(float);  // reused: [E][4] or [E]

  detect_kernel<<<1, 256, 0, stream>>>(x, ei, flags);

  hipMemsetAsync(cnt, 0, (size_t)n * sizeof(int), stream);
  count_kernel<<<(E + 255) / 256, 256, 0, stream>>>(ei, E, n, flags, cnt);
  scan_kernel<<<1, 1024, 0, stream>>>(cnt, offb, pos, n);
  fill_kernel<<<(E + 255) / 256, 256, 0, stream>>>(ei, E, n, flags, pos, bsrc, bdst);

  int gm = (n + 127) / 128;
  int ge = (E + 255) / 256;
  // h = relu(x @ Wp + bp)  (fp32 out)
  mfma_gemm_kernel<1, 0, true, true><<<dim3(gm, 4), 256, 0, stream>>>(x, Wp, bp, flags, h_buf, n, 256, 256);
  // xw0 = h @ W0  (bf16 out)
  mfma_gemm_kernel<0, 1, false, false><<<dim3(gm, 4), 256, 0, stream>>>(h_buf, W0, nullptr, flags, xw_bf, n, 256, 256);
  al0_kernel<<<n, 256, 0, stream>>>(xw_bf, as0, ad0, flags, als0, ald0, n);
  // edge weights layer 0
  wq0_kernel<<<ge, 256, 0, stream>>>(als0, ald0, bsrc, bdst, (f32x4*)wqbuf, E);
  // layer-0 aggregate + b0 + LN + residual + relu (in-place on h_buf)
  gather0_kernel<<<n, 256, 0, stream>>>(xw_bf, als0, ald0, bsrc, wqbuf, offb, b0, g0, be0, flags, h_buf, n);
  // xw1 = h1 @ W1  (bf16 out)
  mfma_gemm_kernel<0, 1, false, false><<<dim3(gm, 2), 256, 0, stream>>>(h_buf, W1, nullptr, flags, xw_bf, n, 128, 256);
  al1_kernel<<<n, 128, 0, stream>>>(xw_bf, as1, ad1, flags, als1, ald1, n);
  // edge weights layer 1
  wq1_kernel<<<ge, 256, 0, stream>>>(als1, ald1, bsrc, bdst, wqbuf, E);
  // layer-1 aggregate + b1 + LN -> h2 (h_buf as n x 128)
  gather1_kernel<<<n, 256, 0, stream>>>(xw_bf, als1, ald1, bsrc, wqbuf, offb, b1, g1, be1, flags, h_buf, n);
  // pre-norm = h2 @ Wo + bo
  mfma_gemm_kernel<0, 0, false, true><<<dim3(gm, 2), 256, 0, stream>>>(h_buf, Wo, bo, flags, prenorm, n, 128, 128);
  // out = row-normalize
  norm_kernel<<<n, 128, 0, stream>>>(prenorm, outp, n);
}